// Round 1
// 729.655 us; speedup vs baseline: 1.0539x; 1.0539x over previous
//
#include <hip/hip_runtime.h>
#include <hip/hip_bf16.h>
#include <stdint.h>

#define SEQ 2048
#define DIM 1024
#define NB  8

typedef __attribute__((ext_vector_type(8))) __bf16 bf16x8;
typedef __attribute__((ext_vector_type(8))) unsigned short ushort8;
typedef __attribute__((ext_vector_type(4))) float f32x4;

__device__ inline unsigned short f2b(float f) {
  union { float f; uint32_t u; } c; c.f = f;
  uint32_t u = c.u;
  return (unsigned short)((u + 0x7fffu + ((u >> 16) & 1u)) >> 16);
}

__device__ inline void async16(const void* g, void* l) {
  __builtin_amdgcn_global_load_lds((const __attribute__((address_space(1))) uint32_t*)g,
                                   (__attribute__((address_space(3))) uint32_t*)l,
                                   16, 0, 0);
}

// fp32 -> bf16 cast, vectorized x4
__global__ __launch_bounds__(256) void cvt_f32_bf16(const float* __restrict__ in,
                                                    unsigned short* __restrict__ out, int n4) {
  int idx = blockIdx.x * 256 + threadIdx.x;
  int stride = gridDim.x * 256;
  for (int i = idx; i < n4; i += stride) {
    float4 f = ((const float4*)in)[i];
    ushort4 h;
    h.x = f2b(f.x); h.y = f2b(f.y); h.z = f2b(f.z); h.w = f2b(f.w);
    ((ushort4*)out)[i] = h;
  }
}

// ---------------------------------------------------------------------------
// 256x256-tile, BK=64, 8-wave (2Mx4N) 8-phase GEMM (NT: C[m,n]=sum_k A[m,k]B[n,k])
// LDS: per buffer, A and B each stored as two K-half arrays [256 rows][32 k]
// (contiguous per half-tile so global_load_lds stages linearly). T2 swizzle:
// within each 64B row, 16B chunk XOR'd by (row&3)<<4 on BOTH the global source
// (pre-swizzle) and the ds_read address -> conflict-free ds_read_b128.
// Schedule per K-tile t (4 phases, 2 barriers each):
//   P1: read A-ks0(8) + B-ks0 n0,1(2); stage (t+1).Bkh1 -> MFMA ks0 x n0,1
//   P2: read B-ks0 n2,3(2);            stage (t+2).Akh0 -> MFMA ks0 x n2,3
//   P3: read A-ks1(8) + B-ks1 n0,1(2); stage (t+2).Bkh0 -> MFMA ks1 x n0,1
//   P4: read B-ks1 n2,3(2);            stage (t+2).Akh1 -> MFMA ks1 x n2,3
//   group end: s_waitcnt vmcnt(6) (tile t+1 fully landed; 3 half-tiles of t+2
//   in flight), then barrier. Epilogue groups drain with vmcnt(0).
// Stage targets are always regions whose last reader drained in the previous
// phase (reads complete at each phase's lgkmcnt(0), before its end barrier).
// MODE 0: proj   — C bf16 + bias[col]
// MODE 1: scores — C fp32 * scale, skip blocks above diagonal
// MODE 2: PV     — C fp32, Keff = bm0+256 (causal zeros beyond)
// ---------------------------------------------------------------------------
template<int MODE>
__global__ __launch_bounds__(512, 2)
void gemm256(const unsigned short* __restrict__ A,
             const unsigned short* __restrict__ B,
             void* __restrict__ Cv,
             const float* __restrict__ bias,
             int K, int lda, int ldb, int ldc,
             long long aStride, long long bStride, long long cStride,
             float scale)
{
  extern __shared__ __align__(16) unsigned short lds[];  // 131072 B dynamic
  unsigned short* const lA0 = lds;            // 4 * 8192 ushort (buf x kh)
  unsigned short* const lB0 = lds + 4 * 8192;

  // bijective XCD chunk remap (nwg % 8 == 0 for all our grids), N fastest
  const int mT = gridDim.x, nT = gridDim.y;
  const int nwg = mT * nT;
  const int did = blockIdx.y * mT + blockIdx.x;   // dispatch order: x fastest
  const int chunk = nwg >> 3;
  const int tile = (did & 7) * chunk + (did >> 3);
  const int bm = tile / nT;
  const int bn = tile % nT;
  if (MODE == 1 && bn > bm) return;
  const int bm0 = bm << 8;
  const int bn0 = bn << 8;
  const int z = blockIdx.z;
  A += (long long)z * aStride;
  B += (long long)z * bStride;

  const int tid  = threadIdx.x;
  const int lane = tid & 63;
  const int wv   = tid >> 6;
  const int wm   = wv >> 2;        // 0..1  (M half: 128 rows)
  const int wn   = wv & 3;         // 0..3  (N quarter: 64 cols)
  const int l15  = lane & 15;
  const int l4   = lane >> 4;
  const int Keff = (MODE == 2) ? (bm0 + 256) : K;
  const int NT   = Keff >> 6;      // K-tiles of 64 (>= 4 in all modes)

  auto LAh = [&](int buf, int kh) { return lA0 + ((buf << 1) + kh) * 8192; };
  auto LBh = [&](int buf, int kh) { return lB0 + ((buf << 1) + kh) * 8192; };

  // --- staging (global -> LDS, linear dest, pre-swizzled source) ---
  const int rS   = tid >> 2;                       // 0..127
  const int cSrc = ((tid & 3) << 4) ^ ((rS & 3) << 4);  // swizzled byte col in 64B row
  const char* gA0 = (const char*)A + ((size_t)(bm0 + rS) * lda) * 2 + cSrc;
  const char* gA1 = gA0 + (size_t)128 * lda * 2;
  const char* gB0 = (const char*)B + ((size_t)(bn0 + rS) * ldb) * 2 + cSrc;
  const char* gB1 = gB0 + (size_t)128 * ldb * 2;

  auto stageA = [&](int buf, int t64, int kh) {
    size_t ko = (size_t)t64 * 128 + (size_t)(kh << 6);   // bytes along K
    unsigned short* d = LAh(buf, kh);
    async16(gA0 + ko, d + tid * 8);
    async16(gA1 + ko, d + (tid + 512) * 8);
  };
  auto stageB = [&](int buf, int t64, int kh) {
    size_t ko = (size_t)t64 * 128 + (size_t)(kh << 6);
    unsigned short* d = LBh(buf, kh);
    async16(gB0 + ko, d + tid * 8);
    async16(gB1 + ko, d + (tid + 512) * 8);
  };

  // --- fragment LDS byte offsets (swizzled read side) ---
  const int swz = (l4 << 4) ^ ((l15 & 3) << 4);
  int aOff[8], bOff[4];
  #pragma unroll
  for (int m = 0; m < 8; ++m) aOff[m] = ((wm << 7) + (m << 4) + l15) * 64 + swz;
  #pragma unroll
  for (int n = 0; n < 4; ++n) bOff[n] = ((wn << 6) + (n << 4) + l15) * 64 + swz;

  auto rd = [&](const unsigned short* base, int off) -> bf16x8 {
    return __builtin_bit_cast(bf16x8, *(const ushort8*)((const char*)base + off));
  };

  f32x4 acc[8][4] = {};
  bf16x8 aF[8], bFa, bFb;

  // --- prologue: tile0 fully + tile1's A0,B0,A1 (B1 comes at group0.P1) ---
  stageA(0, 0, 0); stageB(0, 0, 0); stageA(0, 0, 1); stageB(0, 0, 1);
  stageA(1, 1, 0); stageB(1, 1, 0); stageA(1, 1, 1);
  asm volatile("s_waitcnt vmcnt(6)" ::: "memory");      // tile0 landed
  __builtin_amdgcn_s_barrier();
  __builtin_amdgcn_sched_barrier(0);

  for (int tt = 0; tt < NT; ++tt) {
    const int buf = tt & 1;
    const unsigned short* a0 = LAh(buf, 0);
    const unsigned short* a1 = LAh(buf, 1);
    const unsigned short* b0 = LBh(buf, 0);
    const unsigned short* b1 = LBh(buf, 1);

    // ---- P1: ks0 x n{0,1} ----
    #pragma unroll
    for (int m = 0; m < 8; ++m) aF[m] = rd(a0, aOff[m]);
    bFa = rd(b0, bOff[0]); bFb = rd(b0, bOff[1]);
    if (tt + 1 < NT) stageB(buf ^ 1, tt + 1, 1);
    __builtin_amdgcn_s_barrier();
    asm volatile("s_waitcnt lgkmcnt(0)" ::: "memory");
    __builtin_amdgcn_sched_barrier(0);
    __builtin_amdgcn_s_setprio(1);
    #pragma unroll
    for (int m = 0; m < 8; ++m) {
      acc[m][0] = __builtin_amdgcn_mfma_f32_16x16x32_bf16(aF[m], bFa, acc[m][0], 0, 0, 0);
      acc[m][1] = __builtin_amdgcn_mfma_f32_16x16x32_bf16(aF[m], bFb, acc[m][1], 0, 0, 0);
    }
    __builtin_amdgcn_s_setprio(0);
    __builtin_amdgcn_s_barrier();
    __builtin_amdgcn_sched_barrier(0);

    // ---- P2: ks0 x n{2,3} ----
    bFa = rd(b0, bOff[2]); bFb = rd(b0, bOff[3]);
    if (tt + 2 < NT) stageA(buf, tt + 2, 0);
    __builtin_amdgcn_s_barrier();
    asm volatile("s_waitcnt lgkmcnt(0)" ::: "memory");
    __builtin_amdgcn_sched_barrier(0);
    __builtin_amdgcn_s_setprio(1);
    #pragma unroll
    for (int m = 0; m < 8; ++m) {
      acc[m][2] = __builtin_amdgcn_mfma_f32_16x16x32_bf16(aF[m], bFa, acc[m][2], 0, 0, 0);
      acc[m][3] = __builtin_amdgcn_mfma_f32_16x16x32_bf16(aF[m], bFb, acc[m][3], 0, 0, 0);
    }
    __builtin_amdgcn_s_setprio(0);
    __builtin_amdgcn_s_barrier();
    __builtin_amdgcn_sched_barrier(0);

    // ---- P3: ks1 x n{0,1} ----
    #pragma unroll
    for (int m = 0; m < 8; ++m) aF[m] = rd(a1, aOff[m]);
    bFa = rd(b1, bOff[0]); bFb = rd(b1, bOff[1]);
    if (tt + 2 < NT) stageB(buf, tt + 2, 0);
    __builtin_amdgcn_s_barrier();
    asm volatile("s_waitcnt lgkmcnt(0)" ::: "memory");
    __builtin_amdgcn_sched_barrier(0);
    __builtin_amdgcn_s_setprio(1);
    #pragma unroll
    for (int m = 0; m < 8; ++m) {
      acc[m][0] = __builtin_amdgcn_mfma_f32_16x16x32_bf16(aF[m], bFa, acc[m][0], 0, 0, 0);
      acc[m][1] = __builtin_amdgcn_mfma_f32_16x16x32_bf16(aF[m], bFb, acc[m][1], 0, 0, 0);
    }
    __builtin_amdgcn_s_setprio(0);
    __builtin_amdgcn_s_barrier();
    __builtin_amdgcn_sched_barrier(0);

    // ---- P4: ks1 x n{2,3} ----
    bFa = rd(b1, bOff[2]); bFb = rd(b1, bOff[3]);
    if (tt + 2 < NT) stageA(buf, tt + 2, 1);
    __builtin_amdgcn_s_barrier();
    asm volatile("s_waitcnt lgkmcnt(0)" ::: "memory");
    __builtin_amdgcn_sched_barrier(0);
    __builtin_amdgcn_s_setprio(1);
    #pragma unroll
    for (int m = 0; m < 8; ++m) {
      acc[m][2] = __builtin_amdgcn_mfma_f32_16x16x32_bf16(aF[m], bFa, acc[m][2], 0, 0, 0);
      acc[m][3] = __builtin_amdgcn_mfma_f32_16x16x32_bf16(aF[m], bFb, acc[m][3], 0, 0, 0);
    }
    __builtin_amdgcn_s_setprio(0);
    // group-end: counted vmcnt (never 0 mid-loop; drain at the tail)
    if (tt + 2 < NT) asm volatile("s_waitcnt vmcnt(6)" ::: "memory");
    else             asm volatile("s_waitcnt vmcnt(0)" ::: "memory");
    __builtin_amdgcn_s_barrier();
    __builtin_amdgcn_sched_barrier(0);
  }

  // --- epilogue: C/D layout col = lane&15, row = (lane>>4)*4 + reg ---
  if (MODE == 0) {
    unsigned short* Ch = (unsigned short*)Cv;
    float bvv[4];
    #pragma unroll
    for (int n = 0; n < 4; ++n) bvv[n] = bias[bn0 + (wn << 6) + (n << 4) + l15];
    #pragma unroll
    for (int m = 0; m < 8; ++m) {
      int rowb = bm0 + (wm << 7) + (m << 4) + (l4 << 2);
      #pragma unroll
      for (int r = 0; r < 4; ++r) {
        int row = rowb + r;
        #pragma unroll
        for (int n = 0; n < 4; ++n) {
          int col = bn0 + (wn << 6) + (n << 4) + l15;
          Ch[(size_t)row * ldc + col] = f2b(acc[m][n][r] + bvv[n]);
        }
      }
    }
  } else {
    float* Cf = (float*)Cv + (long long)z * cStride;
    #pragma unroll
    for (int m = 0; m < 8; ++m) {
      int rowb = bm0 + (wm << 7) + (m << 4) + (l4 << 2);
      #pragma unroll
      for (int r = 0; r < 4; ++r) {
        int row = rowb + r;
        #pragma unroll
        for (int n = 0; n < 4; ++n) {
          int col = bn0 + (wn << 6) + (n << 4) + l15;
          Cf[(size_t)row * ldc + col] = acc[m][n][r] * scale;
        }
      }
    }
  }
}

// per-row causal softmax, in-place fp32 + bf16 copy. One block (256 thr) per row.
__global__ __launch_bounds__(256)
void softmax_causal(float* __restrict__ attnF, unsigned short* __restrict__ attnH) {
  const int S = SEQ;
  int row = blockIdx.x;            // b*S + i
  int i = row & (S - 1);
  float* rp = attnF + (size_t)row * S;
  unsigned short* hp = attnH + (size_t)row * S;
  int len = i + 1;
  int tid = threadIdx.x;
  float vals[8];
  float m = -1e30f;
  #pragma unroll
  for (int it = 0; it < 8; ++it) {
    int j = it * 256 + tid;
    float v = (j < len) ? rp[j] : -1e30f;
    vals[it] = v;
    m = fmaxf(m, v);
  }
  #pragma unroll
  for (int o = 32; o > 0; o >>= 1) m = fmaxf(m, __shfl_xor(m, o, 64));
  __shared__ float red[4];
  int wv = tid >> 6, lane = tid & 63;
  if (lane == 0) red[wv] = m;
  __syncthreads();
  m = fmaxf(fmaxf(red[0], red[1]), fmaxf(red[2], red[3]));
  __syncthreads();
  float s = 0.f;
  #pragma unroll
  for (int it = 0; it < 8; ++it) {
    float e = __expf(vals[it] - m);   // masked lanes: exp(-1e30) -> 0
    vals[it] = e;
    s += e;
  }
  #pragma unroll
  for (int o = 32; o > 0; o >>= 1) s += __shfl_xor(s, o, 64);
  if (lane == 0) red[wv] = s;
  __syncthreads();
  s = red[0] + red[1] + red[2] + red[3];
  float inv = 1.f / s;
  #pragma unroll
  for (int it = 0; it < 8; ++it) {
    float o = vals[it] * inv;
    rp[it * 256 + tid] = o;
    hp[it * 256 + tid] = f2b(o);
  }
}

// per-batch transpose [SEQ][DIM] -> [DIM][SEQ] (bf16)
__global__ void transpose_bf16(const unsigned short* __restrict__ in, unsigned short* __restrict__ out) {
  __shared__ unsigned short tile[32][33];
  size_t zoff = (size_t)blockIdx.z * SEQ * DIM;
  const unsigned short* ip = in + zoff;
  unsigned short* op = out + zoff;
  int c0 = blockIdx.x * 32;
  int r0 = blockIdx.y * 32;
  int tx = threadIdx.x, ty = threadIdx.y;   // (32,8)
  #pragma unroll
  for (int dy = 0; dy < 32; dy += 8)
    tile[ty + dy][tx] = ip[(size_t)(r0 + ty + dy) * DIM + c0 + tx];
  __syncthreads();
  #pragma unroll
  for (int dy = 0; dy < 32; dy += 8)
    op[(size_t)(c0 + ty + dy) * SEQ + r0 + tx] = tile[tx][ty + dy];
}

extern "C" void kernel_launch(void* const* d_in, const int* in_sizes, int n_in,
                              void* d_out, int out_size, void* d_ws, size_t ws_size,
                              hipStream_t stream) {
  (void)in_sizes; (void)n_in; (void)out_size; (void)ws_size;
  const int B = NB, S = SEQ, D = DIM;
  const size_t BSD = (size_t)B * S * D;   // 16,777,216
  const size_t DD  = (size_t)D * D;

  const float* q  = (const float*)d_in[0];
  const float* k  = (const float*)d_in[1];
  const float* v  = (const float*)d_in[2];
  const float* Wq = (const float*)d_in[3];
  const float* bq = (const float*)d_in[4];
  const float* Wk = (const float*)d_in[5];
  const float* bk = (const float*)d_in[6];
  const float* Wv = (const float*)d_in[7];
  const float* bv = (const float*)d_in[8];

  float* out   = (float*)d_out;       // [B,S,D]
  float* attnF = out + BSD;           // [B,S,S]

  // ws layout (ushort elems): xb(BSD) | Wqb(DD) Wkb(DD) Wvb(DD) | qp(BSD) | kp(BSD) | vp/attnH(BSS)
  unsigned short* xb  = (unsigned short*)d_ws;        // bf16 input scratch, later vpT
  unsigned short* Wqb = xb + BSD;
  unsigned short* Wkb = Wqb + DD;
  unsigned short* Wvb = Wkb + DD;
  unsigned short* qp  = Wvb + DD;
  unsigned short* kp  = qp + BSD;
  unsigned short* vp  = kp + BSD;
  unsigned short* attnH = vp;                          // overlaps vp (vp dead after transpose)

  // opt-in to 128 KiB dynamic LDS (once)
  static bool attrDone = []() {
    hipFuncSetAttribute(reinterpret_cast<const void*>(&gemm256<0>),
                        hipFuncAttributeMaxDynamicSharedMemorySize, 131072);
    hipFuncSetAttribute(reinterpret_cast<const void*>(&gemm256<1>),
                        hipFuncAttributeMaxDynamicSharedMemorySize, 131072);
    hipFuncSetAttribute(reinterpret_cast<const void*>(&gemm256<2>),
                        hipFuncAttributeMaxDynamicSharedMemorySize, 131072);
    return true;
  }();
  (void)attrDone;

  dim3 blk(256);
  dim3 gblk(512);
  const size_t GLDS = 131072;
  // cast weights
  cvt_f32_bf16<<<dim3(512), blk, 0, stream>>>(Wq, Wqb, (int)(DD / 4));
  cvt_f32_bf16<<<dim3(512), blk, 0, stream>>>(Wk, Wkb, (int)(DD / 4));
  cvt_f32_bf16<<<dim3(512), blk, 0, stream>>>(Wv, Wvb, (int)(DD / 4));
  // projections (xb reused serially; stream-ordered). M=16384 flat, N=1024.
  cvt_f32_bf16<<<dim3(4096), blk, 0, stream>>>(q, xb, (int)(BSD / 4));
  gemm256<0><<<dim3(64, 4, 1), gblk, GLDS, stream>>>(xb, Wqb, qp, bq, D, D, D, D, 0, 0, 0, 1.f);
  cvt_f32_bf16<<<dim3(4096), blk, 0, stream>>>(k, xb, (int)(BSD / 4));
  gemm256<0><<<dim3(64, 4, 1), gblk, GLDS, stream>>>(xb, Wkb, kp, bk, D, D, D, D, 0, 0, 0, 1.f);
  cvt_f32_bf16<<<dim3(4096), blk, 0, stream>>>(v, xb, (int)(BSD / 4));
  gemm256<0><<<dim3(64, 4, 1), gblk, GLDS, stream>>>(xb, Wvb, vp, bv, D, D, D, D, 0, 0, 0, 1.f);
  // vp -> vpT (into xb)
  transpose_bf16<<<dim3(D / 32, S / 32, B), dim3(32, 8), 0, stream>>>(vp, xb);
  // scores: attnF = qp @ kp^T / 32 (lower-triangular blocks only)
  gemm256<1><<<dim3(S / 256, S / 256, B), gblk, GLDS, stream>>>(qp, kp, attnF, nullptr,
      D, D, D, S, (long long)S * D, (long long)S * D, (long long)S * S, 1.f / 32.f);
  // softmax (in-place fp32, bf16 copy to attnH)
  softmax_causal<<<dim3(B * S), blk, 0, stream>>>(attnF, attnH);
  // out = attn @ vp  (B operand is vpT, NT; Keff capped per row-block)
  gemm256<2><<<dim3(S / 256, D / 256, B), gblk, GLDS, stream>>>(attnH, xb, out, nullptr,
      S, S, S, D, (long long)S * S, (long long)D * S, (long long)S * D, 1.f);
}

// Round 2
// 725.878 us; speedup vs baseline: 1.0594x; 1.0052x over previous
//
#include <hip/hip_runtime.h>
#include <hip/hip_bf16.h>
#include <stdint.h>

#define SEQ 2048
#define DIM 1024
#define NB  8

typedef __attribute__((ext_vector_type(8))) __bf16 bf16x8;
typedef __attribute__((ext_vector_type(8))) unsigned short ushort8;
typedef __attribute__((ext_vector_type(4))) float f32x4;

__device__ inline unsigned short f2b(float f) {
  union { float f; uint32_t u; } c; c.f = f;
  uint32_t u = c.u;
  return (unsigned short)((u + 0x7fffu + ((u >> 16) & 1u)) >> 16);
}

__device__ inline void async16(const void* g, void* l) {
  __builtin_amdgcn_global_load_lds((const __attribute__((address_space(1))) uint32_t*)g,
                                   (__attribute__((address_space(3))) uint32_t*)l,
                                   16, 0, 0);
}

// fp32 -> bf16 cast, vectorized x4 (single source)
__global__ __launch_bounds__(256) void cvt_f32_bf16(const float* __restrict__ in,
                                                    unsigned short* __restrict__ out, int n4) {
  int idx = blockIdx.x * 256 + threadIdx.x;
  int stride = gridDim.x * 256;
  for (int i = idx; i < n4; i += stride) {
    float4 f = ((const float4*)in)[i];
    ushort4 h;
    h.x = f2b(f.x); h.y = f2b(f.y); h.z = f2b(f.z); h.w = f2b(f.w);
    ((ushort4*)out)[i] = h;
  }
}

// fp32 -> bf16 cast, three sources -> contiguous dst (z selects source)
__global__ __launch_bounds__(256) void cvt3_f32_bf16(const float* __restrict__ s0,
                                                     const float* __restrict__ s1,
                                                     const float* __restrict__ s2,
                                                     unsigned short* __restrict__ out, int n4) {
  const float* src = (blockIdx.y == 0) ? s0 : (blockIdx.y == 1) ? s1 : s2;
  unsigned short* dst = out + (size_t)blockIdx.y * (size_t)n4 * 4;
  int idx = blockIdx.x * 256 + threadIdx.x;
  int stride = gridDim.x * 256;
  for (int i = idx; i < n4; i += stride) {
    float4 f = ((const float4*)src)[i];
    ushort4 h;
    h.x = f2b(f.x); h.y = f2b(f.y); h.z = f2b(f.z); h.w = f2b(f.w);
    ((ushort4*)dst)[i] = h;
  }
}

// ---------------------------------------------------------------------------
// 256x256-tile, BK=64, 8-wave (2Mx4N) phased GEMM (NT: C[m,n]=sum_k A[m,k]B[n,k])
// LDS: per buffer, A and B each as two K-half arrays [256 rows][32 k], linear
// dest for global_load_lds; T2 swizzle on global source + ds_read addr.
// Per K-tile t (6 barriers):
//   P1: read a0(8)+b0(4); stage (t+1).Bkh1 | bar | lgkm | MFMA ks0 x n01 | bar
//   P2: stage (t+2).Akh0 | MFMA ks0 x n23 (frags from P1) | bar
//   P3: read a1(8)+b1(4); stage (t+2).Bkh0 | bar | lgkm | MFMA ks1 x n01 | bar
//   P4: stage (t+2).Akh1 | MFMA ks1 x n23 | vmcnt(6) | bar
// Hazards: every stage targets a region whose last readers completed before a
// preceding barrier (P1/P3 end barriers follow all-wave lgkmcnt(0)).
// vmcnt(6): 8 stage-ops issued per tile; at tile end the 8 oldest (= tile t+1's
// 4 half-tiles) have landed, tile t+2's 6 ops remain in flight. Tail drains 0.
// MODE 0: proj   — C bf16 + bias[col], batched over z (A/B/C strides, 3 biases)
// MODE 1: scores — C fp32 * scale, skip blocks above diagonal
// MODE 2: PV     — C fp32, Keff = bm0+256 (causal zeros beyond)
// ---------------------------------------------------------------------------
template<int MODE>
__global__ __launch_bounds__(512, 2)
void gemm256(const unsigned short* __restrict__ A,
             const unsigned short* __restrict__ B,
             void* __restrict__ Cv,
             const float* __restrict__ bias0,
             const float* __restrict__ bias1,
             const float* __restrict__ bias2,
             int K, int lda, int ldb, int ldc,
             long long aStride, long long bStride, long long cStride,
             float scale)
{
  extern __shared__ __align__(16) unsigned short lds[];  // 131072 B dynamic
  unsigned short* const lA0 = lds;            // 4 * 8192 ushort (buf x kh)
  unsigned short* const lB0 = lds + 4 * 8192;

  // bijective XCD chunk remap (nwg % 8 == 0 for all our grids), N fastest
  const int mT = gridDim.x, nT = gridDim.y;
  const int nwg = mT * nT;
  const int did = blockIdx.y * mT + blockIdx.x;   // dispatch order: x fastest
  const int chunk = nwg >> 3;
  const int tile = (did & 7) * chunk + (did >> 3);
  const int bm = tile / nT;
  const int bn = tile % nT;
  if (MODE == 1 && bn > bm) return;
  const int bm0 = bm << 8;
  const int bn0 = bn << 8;
  const int z = blockIdx.z;
  A += (long long)z * aStride;
  B += (long long)z * bStride;

  const int tid  = threadIdx.x;
  const int lane = tid & 63;
  const int wv   = tid >> 6;
  const int wm   = wv >> 2;        // 0..1  (M half: 128 rows)
  const int wn   = wv & 3;         // 0..3  (N quarter: 64 cols)
  const int l15  = lane & 15;
  const int l4   = lane >> 4;
  const int Keff = (MODE == 2) ? (bm0 + 256) : K;
  const int NT   = Keff >> 6;      // K-tiles of 64 (>= 4 in all modes)

  auto LAh = [&](int buf, int kh) { return lA0 + ((buf << 1) + kh) * 8192; };
  auto LBh = [&](int buf, int kh) { return lB0 + ((buf << 1) + kh) * 8192; };

  // --- staging (global -> LDS, linear dest, pre-swizzled source) ---
  const int rS   = tid >> 2;                       // 0..127
  const int cSrc = ((tid & 3) << 4) ^ ((rS & 3) << 4);  // swizzled byte col in 64B row
  const char* gA0 = (const char*)A + ((size_t)(bm0 + rS) * lda) * 2 + cSrc;
  const char* gA1 = gA0 + (size_t)128 * lda * 2;
  const char* gB0 = (const char*)B + ((size_t)(bn0 + rS) * ldb) * 2 + cSrc;
  const char* gB1 = gB0 + (size_t)128 * ldb * 2;

  auto stageA = [&](int buf, int t64, int kh) {
    size_t ko = (size_t)t64 * 128 + (size_t)(kh << 6);   // bytes along K
    unsigned short* d = LAh(buf, kh);
    async16(gA0 + ko, d + tid * 8);
    async16(gA1 + ko, d + (tid + 512) * 8);
  };
  auto stageB = [&](int buf, int t64, int kh) {
    size_t ko = (size_t)t64 * 128 + (size_t)(kh << 6);
    unsigned short* d = LBh(buf, kh);
    async16(gB0 + ko, d + tid * 8);
    async16(gB1 + ko, d + (tid + 512) * 8);
  };

  // --- fragment LDS byte offsets (swizzled read side) ---
  const int swz = (l4 << 4) ^ ((l15 & 3) << 4);
  int aOff[8], bOff[4];
  #pragma unroll
  for (int m = 0; m < 8; ++m) aOff[m] = ((wm << 7) + (m << 4) + l15) * 64 + swz;
  #pragma unroll
  for (int n = 0; n < 4; ++n) bOff[n] = ((wn << 6) + (n << 4) + l15) * 64 + swz;

  auto rd = [&](const unsigned short* base, int off) -> bf16x8 {
    return __builtin_bit_cast(bf16x8, *(const ushort8*)((const char*)base + off));
  };

  f32x4 acc[8][4] = {};
  bf16x8 aF[8], bF[4];

  // --- prologue: tile0 fully + tile1's A0,B0,A1 (B1 comes at tile0.P1) ---
  stageA(0, 0, 0); stageB(0, 0, 0); stageA(0, 0, 1); stageB(0, 0, 1);
  stageA(1, 1, 0); stageB(1, 1, 0); stageA(1, 1, 1);
  asm volatile("s_waitcnt vmcnt(6)" ::: "memory");      // tile0 landed
  __builtin_amdgcn_s_barrier();
  __builtin_amdgcn_sched_barrier(0);

  for (int tt = 0; tt < NT; ++tt) {
    const int buf = tt & 1;
    const unsigned short* a0 = LAh(buf, 0);
    const unsigned short* a1 = LAh(buf, 1);
    const unsigned short* b0 = LBh(buf, 0);
    const unsigned short* b1 = LBh(buf, 1);

    // ---- P1: read ks0 frags (a 8 + b all 4); MFMA ks0 x n{0,1} ----
    #pragma unroll
    for (int m = 0; m < 8; ++m) aF[m] = rd(a0, aOff[m]);
    #pragma unroll
    for (int n = 0; n < 4; ++n) bF[n] = rd(b0, bOff[n]);
    if (tt + 1 < NT) stageB(buf ^ 1, tt + 1, 1);
    __builtin_amdgcn_s_barrier();
    asm volatile("s_waitcnt lgkmcnt(0)" ::: "memory");
    __builtin_amdgcn_sched_barrier(0);
    __builtin_amdgcn_s_setprio(1);
    #pragma unroll
    for (int m = 0; m < 8; ++m) {
      acc[m][0] = __builtin_amdgcn_mfma_f32_16x16x32_bf16(aF[m], bF[0], acc[m][0], 0, 0, 0);
      acc[m][1] = __builtin_amdgcn_mfma_f32_16x16x32_bf16(aF[m], bF[1], acc[m][1], 0, 0, 0);
    }
    __builtin_amdgcn_s_setprio(0);
    __builtin_amdgcn_s_barrier();
    __builtin_amdgcn_sched_barrier(0);

    // ---- P2: pure MFMA ks0 x n{2,3} (frags already in regs) ----
    if (tt + 2 < NT) stageA(buf, tt + 2, 0);
    __builtin_amdgcn_s_setprio(1);
    #pragma unroll
    for (int m = 0; m < 8; ++m) {
      acc[m][2] = __builtin_amdgcn_mfma_f32_16x16x32_bf16(aF[m], bF[2], acc[m][2], 0, 0, 0);
      acc[m][3] = __builtin_amdgcn_mfma_f32_16x16x32_bf16(aF[m], bF[3], acc[m][3], 0, 0, 0);
    }
    __builtin_amdgcn_s_setprio(0);
    __builtin_amdgcn_s_barrier();
    __builtin_amdgcn_sched_barrier(0);

    // ---- P3: read ks1 frags; MFMA ks1 x n{0,1} ----
    #pragma unroll
    for (int m = 0; m < 8; ++m) aF[m] = rd(a1, aOff[m]);
    #pragma unroll
    for (int n = 0; n < 4; ++n) bF[n] = rd(b1, bOff[n]);
    if (tt + 2 < NT) stageB(buf, tt + 2, 0);
    __builtin_amdgcn_s_barrier();
    asm volatile("s_waitcnt lgkmcnt(0)" ::: "memory");
    __builtin_amdgcn_sched_barrier(0);
    __builtin_amdgcn_s_setprio(1);
    #pragma unroll
    for (int m = 0; m < 8; ++m) {
      acc[m][0] = __builtin_amdgcn_mfma_f32_16x16x32_bf16(aF[m], bF[0], acc[m][0], 0, 0, 0);
      acc[m][1] = __builtin_amdgcn_mfma_f32_16x16x32_bf16(aF[m], bF[1], acc[m][1], 0, 0, 0);
    }
    __builtin_amdgcn_s_setprio(0);
    __builtin_amdgcn_s_barrier();
    __builtin_amdgcn_sched_barrier(0);

    // ---- P4: pure MFMA ks1 x n{2,3}; tile-end counted vmcnt ----
    if (tt + 2 < NT) stageA(buf, tt + 2, 1);
    __builtin_amdgcn_s_setprio(1);
    #pragma unroll
    for (int m = 0; m < 8; ++m) {
      acc[m][2] = __builtin_amdgcn_mfma_f32_16x16x32_bf16(aF[m], bF[2], acc[m][2], 0, 0, 0);
      acc[m][3] = __builtin_amdgcn_mfma_f32_16x16x32_bf16(aF[m], bF[3], acc[m][3], 0, 0, 0);
    }
    __builtin_amdgcn_s_setprio(0);
    if (tt + 2 < NT) asm volatile("s_waitcnt vmcnt(6)" ::: "memory");
    else             asm volatile("s_waitcnt vmcnt(0)" ::: "memory");
    __builtin_amdgcn_s_barrier();
    __builtin_amdgcn_sched_barrier(0);
  }

  // --- epilogue: C/D layout col = lane&15, row = (lane>>4)*4 + reg ---
  if (MODE == 0) {
    unsigned short* Ch = (unsigned short*)Cv + (long long)z * cStride;
    const float* bp = (z == 0) ? bias0 : (z == 1) ? bias1 : bias2;
    float bvv[4];
    #pragma unroll
    for (int n = 0; n < 4; ++n) bvv[n] = bp[bn0 + (wn << 6) + (n << 4) + l15];
    #pragma unroll
    for (int m = 0; m < 8; ++m) {
      int rowb = bm0 + (wm << 7) + (m << 4) + (l4 << 2);
      #pragma unroll
      for (int r = 0; r < 4; ++r) {
        int row = rowb + r;
        #pragma unroll
        for (int n = 0; n < 4; ++n) {
          int col = bn0 + (wn << 6) + (n << 4) + l15;
          Ch[(size_t)row * ldc + col] = f2b(acc[m][n][r] + bvv[n]);
        }
      }
    }
  } else {
    float* Cf = (float*)Cv + (long long)z * cStride;
    #pragma unroll
    for (int m = 0; m < 8; ++m) {
      int rowb = bm0 + (wm << 7) + (m << 4) + (l4 << 2);
      #pragma unroll
      for (int r = 0; r < 4; ++r) {
        int row = rowb + r;
        #pragma unroll
        for (int n = 0; n < 4; ++n) {
          int col = bn0 + (wn << 6) + (n << 4) + l15;
          Cf[(size_t)row * ldc + col] = acc[m][n][r] * scale;
        }
      }
    }
  }
}

// per-row causal softmax, in-place fp32 + bf16 copy. One block (256 thr) per row.
__global__ __launch_bounds__(256)
void softmax_causal(float* __restrict__ attnF, unsigned short* __restrict__ attnH) {
  const int S = SEQ;
  int row = blockIdx.x;            // b*S + i
  int i = row & (S - 1);
  float* rp = attnF + (size_t)row * S;
  unsigned short* hp = attnH + (size_t)row * S;
  int len = i + 1;
  int tid = threadIdx.x;
  float vals[8];
  float m = -1e30f;
  #pragma unroll
  for (int it = 0; it < 8; ++it) {
    int j = it * 256 + tid;
    float v = (j < len) ? rp[j] : -1e30f;
    vals[it] = v;
    m = fmaxf(m, v);
  }
  #pragma unroll
  for (int o = 32; o > 0; o >>= 1) m = fmaxf(m, __shfl_xor(m, o, 64));
  __shared__ float red[4];
  int wv = tid >> 6, lane = tid & 63;
  if (lane == 0) red[wv] = m;
  __syncthreads();
  m = fmaxf(fmaxf(red[0], red[1]), fmaxf(red[2], red[3]));
  __syncthreads();
  float s = 0.f;
  #pragma unroll
  for (int it = 0; it < 8; ++it) {
    float e = __expf(vals[it] - m);   // masked lanes: exp(-1e30) -> 0
    vals[it] = e;
    s += e;
  }
  #pragma unroll
  for (int o = 32; o > 0; o >>= 1) s += __shfl_xor(s, o, 64);
  if (lane == 0) red[wv] = s;
  __syncthreads();
  s = red[0] + red[1] + red[2] + red[3];
  float inv = 1.f / s;
  #pragma unroll
  for (int it = 0; it < 8; ++it) {
    float o = vals[it] * inv;
    rp[it * 256 + tid] = o;
    hp[it * 256 + tid] = f2b(o);
  }
}

// per-batch transpose [SEQ][DIM] -> [DIM][SEQ] (bf16), 64x64 tiles, ushort8 I/O.
// LDS stored transposed: tile[c][ r ^ (((c>>3)&7)<<3) ] with pad 72 — the XOR on
// the r-index (keyed by c's HIGH bits, which vary across lanes within a store)
// spreads the scatter-writes over all 32 banks (2 lanes/bank = free).
__global__ __launch_bounds__(256)
void transpose64_bf16(const unsigned short* __restrict__ in, unsigned short* __restrict__ out) {
  __shared__ unsigned short tile[64][72];
  size_t zoff = (size_t)blockIdx.z * SEQ * DIM;
  const unsigned short* ip = in + zoff;
  unsigned short* op = out + zoff;
  int c0 = blockIdx.x * 64;   // DIM
  int r0 = blockIdx.y * 64;   // SEQ
  int tid = threadIdx.x;
  #pragma unroll
  for (int p = 0; p < 2; ++p) {
    int e = tid + p * 256;
    int row = e >> 3;              // 0..63 within r
    int cv  = (e & 7) << 3;        // 0..56 within c, step 8
    ushort8 v = *(const ushort8*)&ip[(size_t)(r0 + row) * DIM + c0 + cv];
    #pragma unroll
    for (int j = 0; j < 8; ++j) {
      int c = cv + j;
      tile[c][row ^ (((c >> 3) & 7) << 3)] = v[j];
    }
  }
  __syncthreads();
  #pragma unroll
  for (int p = 0; p < 2; ++p) {
    int e = tid + p * 256;
    int orow = e >> 3;             // c-dim index
    int ocv  = (e & 7) << 3;       // r-dim start, step 8
    int osw  = ocv ^ (((orow >> 3) & 7) << 3);
    ushort8 v = *(const ushort8*)&tile[orow][osw];
    *(ushort8*)&op[(size_t)(c0 + orow) * SEQ + r0 + ocv] = v;
  }
}

extern "C" void kernel_launch(void* const* d_in, const int* in_sizes, int n_in,
                              void* d_out, int out_size, void* d_ws, size_t ws_size,
                              hipStream_t stream) {
  (void)in_sizes; (void)n_in; (void)out_size;
  const int B = NB, S = SEQ, D = DIM;
  const size_t BSD = (size_t)B * S * D;   // 16,777,216
  const size_t BSS = (size_t)B * S * S;   // 33,554,432
  const size_t DD  = (size_t)D * D;

  const float* q  = (const float*)d_in[0];
  const float* k  = (const float*)d_in[1];
  const float* v  = (const float*)d_in[2];
  const float* Wq = (const float*)d_in[3];
  const float* bq = (const float*)d_in[4];
  const float* Wk = (const float*)d_in[5];
  const float* bk = (const float*)d_in[6];
  const float* Wv = (const float*)d_in[7];
  const float* bv = (const float*)d_in[8];

  float* out   = (float*)d_out;       // [B,S,D]
  float* attnF = out + BSD;           // [B,S,S]

  // opt-in to 128 KiB dynamic LDS (once)
  static bool attrDone = []() {
    hipFuncSetAttribute(reinterpret_cast<const void*>(&gemm256<0>),
                        hipFuncAttributeMaxDynamicSharedMemorySize, 131072);
    hipFuncSetAttribute(reinterpret_cast<const void*>(&gemm256<1>),
                        hipFuncAttributeMaxDynamicSharedMemorySize, 131072);
    hipFuncSetAttribute(reinterpret_cast<const void*>(&gemm256<2>),
                        hipFuncAttributeMaxDynamicSharedMemorySize, 131072);
    return true;
  }();
  (void)attrDone;

  dim3 blk(256);
  dim3 gblk(512);
  const size_t GLDS = 131072;

  const size_t needBig = (5 * BSD + 3 * DD + BSS) * 2;   // bytes, ~230 MB
  if (ws_size >= needBig) {
    // big layout: qb kb vb | Wqb Wkb Wvb | qp kp | vp/attnH ; vpT reuses qb
    unsigned short* qb  = (unsigned short*)d_ws;
    unsigned short* kb  = qb + BSD;
    unsigned short* vb  = kb + BSD;
    unsigned short* Wqb = vb + BSD;
    unsigned short* qp  = Wqb + 3 * DD;
    unsigned short* kp  = qp + BSD;
    unsigned short* vp  = kp + BSD;       // inside BSS-sized region
    unsigned short* attnH = vp;
    unsigned short* vpT = qb;             // qb dead after projections

    // casts: weights (3x) and inputs (3x), one launch each
    cvt3_f32_bf16<<<dim3(512, 3), blk, 0, stream>>>(Wq, Wk, Wv, Wqb, (int)(DD / 4));
    cvt3_f32_bf16<<<dim3(4096, 3), blk, 0, stream>>>(q, k, v, qb, (int)(BSD / 4));
    // batched projections: z=0..2 -> {q,k,v}
    gemm256<0><<<dim3(64, 4, 3), gblk, GLDS, stream>>>(qb, Wqb, qp, bq, bk, bv,
        D, D, D, D, (long long)BSD, (long long)DD, (long long)BSD, 1.f);
    // vp -> vpT
    transpose64_bf16<<<dim3(D / 64, S / 64, B), blk, 0, stream>>>(vp, vpT);
    // scores
    gemm256<1><<<dim3(S / 256, S / 256, B), gblk, GLDS, stream>>>(qp, kp, attnF,
        nullptr, nullptr, nullptr,
        D, D, D, S, (long long)S * D, (long long)S * D, (long long)S * S, 1.f / 32.f);
    softmax_causal<<<dim3(B * S), blk, 0, stream>>>(attnF, attnH);
    gemm256<2><<<dim3(S / 256, D / 256, B), gblk, GLDS, stream>>>(attnH, vpT, out,
        nullptr, nullptr, nullptr,
        S, S, S, D, (long long)S * S, (long long)D * S, (long long)S * D, 1.f);
  } else {
    // fallback serial layout: xb | Wqb Wkb Wvb | qp | kp | vp/attnH
    unsigned short* xb  = (unsigned short*)d_ws;
    unsigned short* Wqb = xb + BSD;
    unsigned short* Wkb = Wqb + DD;
    unsigned short* Wvb = Wkb + DD;
    unsigned short* qp  = Wvb + DD;
    unsigned short* kp  = qp + BSD;
    unsigned short* vp  = kp + BSD;
    unsigned short* attnH = vp;

    cvt3_f32_bf16<<<dim3(512, 3), blk, 0, stream>>>(Wq, Wk, Wv, Wqb, (int)(DD / 4));
    cvt_f32_bf16<<<dim3(4096), blk, 0, stream>>>(q, xb, (int)(BSD / 4));
    gemm256<0><<<dim3(64, 4, 1), gblk, GLDS, stream>>>(xb, Wqb, qp, bq, bq, bq,
        D, D, D, D, 0, 0, 0, 1.f);
    cvt_f32_bf16<<<dim3(4096), blk, 0, stream>>>(k, xb, (int)(BSD / 4));
    gemm256<0><<<dim3(64, 4, 1), gblk, GLDS, stream>>>(xb, Wqb + DD, kp, bk, bk, bk,
        D, D, D, D, 0, 0, 0, 1.f);
    cvt_f32_bf16<<<dim3(4096), blk, 0, stream>>>(v, xb, (int)(BSD / 4));
    gemm256<0><<<dim3(64, 4, 1), gblk, GLDS, stream>>>(xb, Wvb, vp, bv, bv, bv,
        D, D, D, D, 0, 0, 0, 1.f);
    transpose64_bf16<<<dim3(D / 64, S / 64, B), blk, 0, stream>>>(vp, xb);
    gemm256<1><<<dim3(S / 256, S / 256, B), gblk, GLDS, stream>>>(qp, kp, attnF,
        nullptr, nullptr, nullptr,
        D, D, D, S, (long long)S * D, (long long)S * D, (long long)S * S, 1.f / 32.f);
    softmax_causal<<<dim3(B * S), blk, 0, stream>>>(attnF, attnH);
    gemm256<2><<<dim3(S / 256, D / 256, B), gblk, GLDS, stream>>>(attnH, xb, out,
        nullptr, nullptr, nullptr,
        S, S, S, D, (long long)S * S, (long long)D * S, (long long)S * D, 1.f);
  }
}

// Round 5
// 699.105 us; speedup vs baseline: 1.1000x; 1.0383x over previous
//
#include <hip/hip_runtime.h>
#include <hip/hip_bf16.h>
#include <stdint.h>

#define SEQ 2048
#define DIM 1024
#define NB  8

typedef __attribute__((ext_vector_type(8))) __bf16 bf16x8;
typedef __attribute__((ext_vector_type(8))) unsigned short ushort8;
typedef __attribute__((ext_vector_type(4))) float f32x4;

__device__ inline unsigned short f2b(float f) {
  union { float f; uint32_t u; } c; c.f = f;
  uint32_t u = c.u;
  return (unsigned short)((u + 0x7fffu + ((u >> 16) & 1u)) >> 16);
}

__device__ inline void async16(const void* g, void* l) {
  __builtin_amdgcn_global_load_lds((const __attribute__((address_space(1))) uint32_t*)g,
                                   (__attribute__((address_space(3))) uint32_t*)l,
                                   16, 0, 0);
}

// fp32 -> bf16 cast, vectorized x4 (single source)
__global__ __launch_bounds__(256) void cvt_f32_bf16(const float* __restrict__ in,
                                                    unsigned short* __restrict__ out, int n4) {
  int idx = blockIdx.x * 256 + threadIdx.x;
  int stride = gridDim.x * 256;
  for (int i = idx; i < n4; i += stride) {
    float4 f = ((const float4*)in)[i];
    ushort4 h;
    h.x = f2b(f.x); h.y = f2b(f.y); h.z = f2b(f.z); h.w = f2b(f.w);
    ((ushort4*)out)[i] = h;
  }
}

// fp32 -> bf16 cast, three sources -> contiguous dst (z selects source)
__global__ __launch_bounds__(256) void cvt3_f32_bf16(const float* __restrict__ s0,
                                                     const float* __restrict__ s1,
                                                     const float* __restrict__ s2,
                                                     unsigned short* __restrict__ out, int n4) {
  const float* src = (blockIdx.y == 0) ? s0 : (blockIdx.y == 1) ? s1 : s2;
  unsigned short* dst = out + (size_t)blockIdx.y * (size_t)n4 * 4;
  int idx = blockIdx.x * 256 + threadIdx.x;
  int stride = gridDim.x * 256;
  for (int i = idx; i < n4; i += stride) {
    float4 f = ((const float4*)src)[i];
    ushort4 h;
    h.x = f2b(f.x); h.y = f2b(f.y); h.z = f2b(f.z); h.w = f2b(f.w);
    ((ushort4*)dst)[i] = h;
  }
}

// ---------------------------------------------------------------------------
// 256x256-tile, BK=64, 8-wave (2Mx4N) phased GEMM (NT: C[m,n]=sum_k A[m,k]B[n,k])
// LDS: per buffer, A and B each as two K-half arrays [256 rows][32 k], linear
// dest for global_load_lds; swizzle on global source + ds_read addr.
// BANK MATH (the round-2 fix): row stride = 64B = 16 banks, so bank group is
// determined by (row&1, chunk). Swizzle key must be INDEPENDENT of row bit 0:
// key(r) = (r>>1)&3. Then a b128 phase's lanes cover all 8 (parity,chunk)
// 4-bank groups exactly once -> conflict-free. (Old key r&3 contained the
// parity bit -> 4 groups -> conflicts: 9.4M SQ_LDS_BANK_CONFLICT, MfmaUtil 33%.)
// Per K-tile t (6 barriers):
//   P1: read a0(8)+b0(4); stage (t+1).Bkh1 | bar | lgkm | MFMA ks0 x n01 | bar
//   P2: stage (t+2).Akh0 | MFMA ks0 x n23 (frags from P1) | bar
//   P3: read a1(8)+b1(4); stage (t+2).Bkh0 | bar | lgkm | MFMA ks1 x n01 | bar
//   P4: stage (t+2).Akh1 | MFMA ks1 x n23 | vmcnt(6) | bar
// MODE 0: proj   — C bf16 + bias[col], batched over z (A/B/C strides, 3 biases)
// MODE 1: scores — C fp32 * scale, skip blocks above diagonal
// MODE 2: PV     — C fp32, Keff = bm0+256 (causal zeros beyond)
// ---------------------------------------------------------------------------
template<int MODE>
__global__ __launch_bounds__(512, 2)
void gemm256(const unsigned short* __restrict__ A,
             const unsigned short* __restrict__ B,
             void* __restrict__ Cv,
             const float* __restrict__ bias0,
             const float* __restrict__ bias1,
             const float* __restrict__ bias2,
             int K, int lda, int ldb, int ldc,
             long long aStride, long long bStride, long long cStride,
             float scale)
{
  extern __shared__ __align__(16) unsigned short lds[];  // 131072 B dynamic
  unsigned short* const lA0 = lds;            // 4 * 8192 ushort (buf x kh)
  unsigned short* const lB0 = lds + 4 * 8192;

  // bijective XCD chunk remap (nwg % 8 == 0 for all our grids), N fastest
  const int mT = gridDim.x, nT = gridDim.y;
  const int nwg = mT * nT;
  const int did = blockIdx.y * mT + blockIdx.x;   // dispatch order: x fastest
  const int chunk = nwg >> 3;
  const int tile = (did & 7) * chunk + (did >> 3);
  const int bm = tile / nT;
  const int bn = tile % nT;
  if (MODE == 1 && bn > bm) return;
  const int bm0 = bm << 8;
  const int bn0 = bn << 8;
  const int z = blockIdx.z;
  A += (long long)z * aStride;
  B += (long long)z * bStride;

  const int tid  = threadIdx.x;
  const int lane = tid & 63;
  const int wv   = tid >> 6;
  const int wm   = wv >> 2;        // 0..1  (M half: 128 rows)
  const int wn   = wv & 3;         // 0..3  (N quarter: 64 cols)
  const int l15  = lane & 15;
  const int l4   = lane >> 4;
  const int Keff = (MODE == 2) ? (bm0 + 256) : K;
  const int NT   = Keff >> 6;      // K-tiles of 64 (>= 4 in all modes)

  auto LAh = [&](int buf, int kh) { return lA0 + ((buf << 1) + kh) * 8192; };
  auto LBh = [&](int buf, int kh) { return lB0 + ((buf << 1) + kh) * 8192; };

  // --- staging (global -> LDS, linear dest, pre-swizzled source) ---
  const int rS   = tid >> 2;                       // 0..127
  const int cSrc = ((tid & 3) << 4) ^ (((rS >> 1) & 3) << 4);  // key=(r>>1)&3
  const char* gA0 = (const char*)A + ((size_t)(bm0 + rS) * lda) * 2 + cSrc;
  const char* gA1 = gA0 + (size_t)128 * lda * 2;   // key(r+128) == key(r)
  const char* gB0 = (const char*)B + ((size_t)(bn0 + rS) * ldb) * 2 + cSrc;
  const char* gB1 = gB0 + (size_t)128 * ldb * 2;

  auto stageA = [&](int buf, int t64, int kh) {
    size_t ko = (size_t)t64 * 128 + (size_t)(kh << 6);   // bytes along K
    unsigned short* d = LAh(buf, kh);
    async16(gA0 + ko, d + tid * 8);
    async16(gA1 + ko, d + (tid + 512) * 8);
  };
  auto stageB = [&](int buf, int t64, int kh) {
    size_t ko = (size_t)t64 * 128 + (size_t)(kh << 6);
    unsigned short* d = LBh(buf, kh);
    async16(gB0 + ko, d + tid * 8);
    async16(gB1 + ko, d + (tid + 512) * 8);
  };

  // --- fragment LDS byte offsets (swizzled read side, key=(r>>1)&3) ---
  const int swz = (l4 << 4) ^ (((l15 >> 1) & 3) << 4);
  int aOff[8], bOff[4];
  #pragma unroll
  for (int m = 0; m < 8; ++m) aOff[m] = ((wm << 7) + (m << 4) + l15) * 64 + swz;
  #pragma unroll
  for (int n = 0; n < 4; ++n) bOff[n] = ((wn << 6) + (n << 4) + l15) * 64 + swz;

  auto rd = [&](const unsigned short* base, int off) -> bf16x8 {
    return __builtin_bit_cast(bf16x8, *(const ushort8*)((const char*)base + off));
  };

  f32x4 acc[8][4] = {};
  bf16x8 aF[8], bF[4];

  // --- prologue: tile0 fully + tile1's A0,B0,A1 (B1 comes at tile0.P1) ---
  stageA(0, 0, 0); stageB(0, 0, 0); stageA(0, 0, 1); stageB(0, 0, 1);
  stageA(1, 1, 0); stageB(1, 1, 0); stageA(1, 1, 1);
  asm volatile("s_waitcnt vmcnt(6)" ::: "memory");      // tile0 landed
  __builtin_amdgcn_s_barrier();
  __builtin_amdgcn_sched_barrier(0);

  for (int tt = 0; tt < NT; ++tt) {
    const int buf = tt & 1;
    const unsigned short* a0 = LAh(buf, 0);
    const unsigned short* a1 = LAh(buf, 1);
    const unsigned short* b0 = LBh(buf, 0);
    const unsigned short* b1 = LBh(buf, 1);

    // ---- P1: read ks0 frags (a 8 + b all 4); MFMA ks0 x n{0,1} ----
    #pragma unroll
    for (int m = 0; m < 8; ++m) aF[m] = rd(a0, aOff[m]);
    #pragma unroll
    for (int n = 0; n < 4; ++n) bF[n] = rd(b0, bOff[n]);
    if (tt + 1 < NT) stageB(buf ^ 1, tt + 1, 1);
    __builtin_amdgcn_s_barrier();
    asm volatile("s_waitcnt lgkmcnt(0)" ::: "memory");
    __builtin_amdgcn_sched_barrier(0);
    __builtin_amdgcn_s_setprio(1);
    #pragma unroll
    for (int m = 0; m < 8; ++m) {
      acc[m][0] = __builtin_amdgcn_mfma_f32_16x16x32_bf16(aF[m], bF[0], acc[m][0], 0, 0, 0);
      acc[m][1] = __builtin_amdgcn_mfma_f32_16x16x32_bf16(aF[m], bF[1], acc[m][1], 0, 0, 0);
    }
    __builtin_amdgcn_s_setprio(0);
    __builtin_amdgcn_s_barrier();
    __builtin_amdgcn_sched_barrier(0);

    // ---- P2: pure MFMA ks0 x n{2,3} (frags already in regs) ----
    if (tt + 2 < NT) stageA(buf, tt + 2, 0);
    __builtin_amdgcn_s_setprio(1);
    #pragma unroll
    for (int m = 0; m < 8; ++m) {
      acc[m][2] = __builtin_amdgcn_mfma_f32_16x16x32_bf16(aF[m], bF[2], acc[m][2], 0, 0, 0);
      acc[m][3] = __builtin_amdgcn_mfma_f32_16x16x32_bf16(aF[m], bF[3], acc[m][3], 0, 0, 0);
    }
    __builtin_amdgcn_s_setprio(0);
    __builtin_amdgcn_s_barrier();
    __builtin_amdgcn_sched_barrier(0);

    // ---- P3: read ks1 frags; MFMA ks1 x n{0,1} ----
    #pragma unroll
    for (int m = 0; m < 8; ++m) aF[m] = rd(a1, aOff[m]);
    #pragma unroll
    for (int n = 0; n < 4; ++n) bF[n] = rd(b1, bOff[n]);
    if (tt + 2 < NT) stageB(buf, tt + 2, 0);
    __builtin_amdgcn_s_barrier();
    asm volatile("s_waitcnt lgkmcnt(0)" ::: "memory");
    __builtin_amdgcn_sched_barrier(0);
    __builtin_amdgcn_s_setprio(1);
    #pragma unroll
    for (int m = 0; m < 8; ++m) {
      acc[m][0] = __builtin_amdgcn_mfma_f32_16x16x32_bf16(aF[m], bF[0], acc[m][0], 0, 0, 0);
      acc[m][1] = __builtin_amdgcn_mfma_f32_16x16x32_bf16(aF[m], bF[1], acc[m][1], 0, 0, 0);
    }
    __builtin_amdgcn_s_setprio(0);
    __builtin_amdgcn_s_barrier();
    __builtin_amdgcn_sched_barrier(0);

    // ---- P4: pure MFMA ks1 x n{2,3}; tile-end counted vmcnt ----
    if (tt + 2 < NT) stageA(buf, tt + 2, 1);
    __builtin_amdgcn_s_setprio(1);
    #pragma unroll
    for (int m = 0; m < 8; ++m) {
      acc[m][2] = __builtin_amdgcn_mfma_f32_16x16x32_bf16(aF[m], bF[2], acc[m][2], 0, 0, 0);
      acc[m][3] = __builtin_amdgcn_mfma_f32_16x16x32_bf16(aF[m], bF[3], acc[m][3], 0, 0, 0);
    }
    __builtin_amdgcn_s_setprio(0);
    if (tt + 2 < NT) asm volatile("s_waitcnt vmcnt(6)" ::: "memory");
    else             asm volatile("s_waitcnt vmcnt(0)" ::: "memory");
    __builtin_amdgcn_s_barrier();
    __builtin_amdgcn_sched_barrier(0);
  }

  // --- epilogue: C/D layout col = lane&15, row = (lane>>4)*4 + reg ---
  if (MODE == 0) {
    unsigned short* Ch = (unsigned short*)Cv + (long long)z * cStride;
    const float* bp = (z == 0) ? bias0 : (z == 1) ? bias1 : bias2;
    float bvv[4];
    #pragma unroll
    for (int n = 0; n < 4; ++n) bvv[n] = bp[bn0 + (wn << 6) + (n << 4) + l15];
    #pragma unroll
    for (int m = 0; m < 8; ++m) {
      int rowb = bm0 + (wm << 7) + (m << 4) + (l4 << 2);
      #pragma unroll
      for (int r = 0; r < 4; ++r) {
        int row = rowb + r;
        #pragma unroll
        for (int n = 0; n < 4; ++n) {
          int col = bn0 + (wn << 6) + (n << 4) + l15;
          Ch[(size_t)row * ldc + col] = f2b(acc[m][n][r] + bvv[n]);
        }
      }
    }
  } else {
    float* Cf = (float*)Cv + (long long)z * cStride;
    #pragma unroll
    for (int m = 0; m < 8; ++m) {
      int rowb = bm0 + (wm << 7) + (m << 4) + (l4 << 2);
      #pragma unroll
      for (int r = 0; r < 4; ++r) {
        int row = rowb + r;
        #pragma unroll
        for (int n = 0; n < 4; ++n) {
          int col = bn0 + (wn << 6) + (n << 4) + l15;
          Cf[(size_t)row * ldc + col] = acc[m][n][r] * scale;
        }
      }
    }
  }
}

// per-row causal softmax, in-place fp32 + bf16 copy. One block (256 thr) per row.
__global__ __launch_bounds__(256)
void softmax_causal(float* __restrict__ attnF, unsigned short* __restrict__ attnH) {
  const int S = SEQ;
  int row = blockIdx.x;            // b*S + i
  int i = row & (S - 1);
  float* rp = attnF + (size_t)row * S;
  unsigned short* hp = attnH + (size_t)row * S;
  int len = i + 1;
  int tid = threadIdx.x;
  float vals[8];
  float m = -1e30f;
  #pragma unroll
  for (int it = 0; it < 8; ++it) {
    int j = it * 256 + tid;
    float v = (j < len) ? rp[j] : -1e30f;
    vals[it] = v;
    m = fmaxf(m, v);
  }
  #pragma unroll
  for (int o = 32; o > 0; o >>= 1) m = fmaxf(m, __shfl_xor(m, o, 64));
  __shared__ float red[4];
  int wv = tid >> 6, lane = tid & 63;
  if (lane == 0) red[wv] = m;
  __syncthreads();
  m = fmaxf(fmaxf(red[0], red[1]), fmaxf(red[2], red[3]));
  __syncthreads();
  float s = 0.f;
  #pragma unroll
  for (int it = 0; it < 8; ++it) {
    float e = __expf(vals[it] - m);   // masked lanes: exp(-1e30) -> 0
    vals[it] = e;
    s += e;
  }
  #pragma unroll
  for (int o = 32; o > 0; o >>= 1) s += __shfl_xor(s, o, 64);
  if (lane == 0) red[wv] = s;
  __syncthreads();
  s = red[0] + red[1] + red[2] + red[3];
  float inv = 1.f / s;
  #pragma unroll
  for (int it = 0; it < 8; ++it) {
    float o = vals[it] * inv;
    rp[it * 256 + tid] = o;
    hp[it * 256 + tid] = f2b(o);
  }
}

// per-batch transpose [SEQ][DIM] -> [DIM][SEQ] (bf16), 64x64 tiles, ushort8 I/O.
__global__ __launch_bounds__(256)
void transpose64_bf16(const unsigned short* __restrict__ in, unsigned short* __restrict__ out) {
  __shared__ unsigned short tile[64][72];
  size_t zoff = (size_t)blockIdx.z * SEQ * DIM;
  const unsigned short* ip = in + zoff;
  unsigned short* op = out + zoff;
  int c0 = blockIdx.x * 64;   // DIM
  int r0 = blockIdx.y * 64;   // SEQ
  int tid = threadIdx.x;
  #pragma unroll
  for (int p = 0; p < 2; ++p) {
    int e = tid + p * 256;
    int row = e >> 3;              // 0..63 within r
    int cv  = (e & 7) << 3;        // 0..56 within c, step 8
    ushort8 v = *(const ushort8*)&ip[(size_t)(r0 + row) * DIM + c0 + cv];
    #pragma unroll
    for (int j = 0; j < 8; ++j) {
      int c = cv + j;
      tile[c][row ^ (((c >> 3) & 7) << 3)] = v[j];
    }
  }
  __syncthreads();
  #pragma unroll
  for (int p = 0; p < 2; ++p) {
    int e = tid + p * 256;
    int orow = e >> 3;             // c-dim index
    int ocv  = (e & 7) << 3;       // r-dim start, step 8
    int osw  = ocv ^ (((orow >> 3) & 7) << 3);
    ushort8 v = *(const ushort8*)&tile[orow][osw];
    *(ushort8*)&op[(size_t)(c0 + orow) * SEQ + r0 + ocv] = v;
  }
}

extern "C" void kernel_launch(void* const* d_in, const int* in_sizes, int n_in,
                              void* d_out, int out_size, void* d_ws, size_t ws_size,
                              hipStream_t stream) {
  (void)in_sizes; (void)n_in; (void)out_size;
  const int B = NB, S = SEQ, D = DIM;
  const size_t BSD = (size_t)B * S * D;   // 16,777,216
  const size_t BSS = (size_t)B * S * S;   // 33,554,432
  const size_t DD  = (size_t)D * D;

  const float* q  = (const float*)d_in[0];
  const float* k  = (const float*)d_in[1];
  const float* v  = (const float*)d_in[2];
  const float* Wq = (const float*)d_in[3];
  const float* bq = (const float*)d_in[4];
  const float* Wk = (const float*)d_in[5];
  const float* bk = (const float*)d_in[6];
  const float* Wv = (const float*)d_in[7];
  const float* bv = (const float*)d_in[8];

  float* out   = (float*)d_out;       // [B,S,D]
  float* attnF = out + BSD;           // [B,S,S]

  // opt-in to 128 KiB dynamic LDS (once)
  static bool attrDone = []() {
    hipFuncSetAttribute(reinterpret_cast<const void*>(&gemm256<0>),
                        hipFuncAttributeMaxDynamicSharedMemorySize, 131072);
    hipFuncSetAttribute(reinterpret_cast<const void*>(&gemm256<1>),
                        hipFuncAttributeMaxDynamicSharedMemorySize, 131072);
    hipFuncSetAttribute(reinterpret_cast<const void*>(&gemm256<2>),
                        hipFuncAttributeMaxDynamicSharedMemorySize, 131072);
    return true;
  }();
  (void)attrDone;

  dim3 blk(256);
  dim3 gblk(512);
  const size_t GLDS = 131072;

  const size_t needBig = (5 * BSD + 3 * DD + BSS) * 2;   // bytes, ~230 MB
  if (ws_size >= needBig) {
    // big layout: qb kb vb | Wqb Wkb Wvb | qp kp | vp/attnH ; vpT reuses qb
    unsigned short* qb  = (unsigned short*)d_ws;
    unsigned short* kb  = qb + BSD;
    unsigned short* vb  = kb + BSD;
    unsigned short* Wqb = vb + BSD;
    unsigned short* qp  = Wqb + 3 * DD;
    unsigned short* kp  = qp + BSD;
    unsigned short* vp  = kp + BSD;       // inside BSS-sized region
    unsigned short* attnH = vp;
    unsigned short* vpT = qb;             // qb dead after projections

    // casts: weights (3x) and inputs (3x), one launch each
    cvt3_f32_bf16<<<dim3(512, 3), blk, 0, stream>>>(Wq, Wk, Wv, Wqb, (int)(DD / 4));
    cvt3_f32_bf16<<<dim3(4096, 3), blk, 0, stream>>>(q, k, v, qb, (int)(BSD / 4));
    // batched projections: z=0..2 -> {q,k,v}
    gemm256<0><<<dim3(64, 4, 3), gblk, GLDS, stream>>>(qb, Wqb, qp, bq, bk, bv,
        D, D, D, D, (long long)BSD, (long long)DD, (long long)BSD, 1.f);
    // vp -> vpT
    transpose64_bf16<<<dim3(D / 64, S / 64, B), blk, 0, stream>>>(vp, vpT);
    // scores
    gemm256<1><<<dim3(S / 256, S / 256, B), gblk, GLDS, stream>>>(qp, kp, attnF,
        nullptr, nullptr, nullptr,
        D, D, D, S, (long long)S * D, (long long)S * D, (long long)S * S, 1.f / 32.f);
    softmax_causal<<<dim3(B * S), blk, 0, stream>>>(attnF, attnH);
    gemm256<2><<<dim3(S / 256, D / 256, B), gblk, GLDS, stream>>>(attnH, vpT, out,
        nullptr, nullptr, nullptr,
        S, S, S, D, (long long)S * S, (long long)D * S, (long long)S * D, 1.f);
  } else {
    // fallback serial layout: xb | Wqb Wkb Wvb | qp | kp | vp/attnH
    unsigned short* xb  = (unsigned short*)d_ws;
    unsigned short* Wqb = xb + BSD;
    unsigned short* Wkb = Wqb + DD;
    unsigned short* Wvb = Wkb + DD;
    unsigned short* qp  = Wvb + DD;
    unsigned short* kp  = qp + BSD;
    unsigned short* vp  = kp + BSD;
    unsigned short* attnH = vp;

    cvt3_f32_bf16<<<dim3(512, 3), blk, 0, stream>>>(Wq, Wk, Wv, Wqb, (int)(DD / 4));
    cvt_f32_bf16<<<dim3(4096), blk, 0, stream>>>(q, xb, (int)(BSD / 4));
    gemm256<0><<<dim3(64, 4, 1), gblk, GLDS, stream>>>(xb, Wqb, qp, bq, bq, bq,
        D, D, D, D, 0, 0, 0, 1.f);
    cvt_f32_bf16<<<dim3(4096), blk, 0, stream>>>(k, xb, (int)(BSD / 4));
    gemm256<0><<<dim3(64, 4, 1), gblk, GLDS, stream>>>(xb, Wqb + DD, kp, bk, bk, bk,
        D, D, D, D, 0, 0, 0, 1.f);
    cvt_f32_bf16<<<dim3(4096), blk, 0, stream>>>(v, xb, (int)(BSD / 4));
    gemm256<0><<<dim3(64, 4, 1), gblk, GLDS, stream>>>(xb, Wvb, vp, bv, bv, bv,
        D, D, D, D, 0, 0, 0, 1.f);
    transpose64_bf16<<<dim3(D / 64, S / 64, B), blk, 0, stream>>>(vp, xb);
    gemm256<1><<<dim3(S / 256, S / 256, B), gblk, GLDS, stream>>>(qp, kp, attnF,
        nullptr, nullptr, nullptr,
        D, D, D, S, (long long)S * D, (long long)S * D, (long long)S * S, 1.f / 32.f);
    softmax_causal<<<dim3(B * S), blk, 0, stream>>>(attnF, attnH);
    gemm256<2><<<dim3(S / 256, D / 256, B), gblk, GLDS, stream>>>(attnH, xb, out,
        nullptr, nullptr, nullptr,
        S, S, S, D, (long long)S * S, (long long)D * S, (long long)S * D, 1.f);
  }
}